// Round 23
// baseline (114.698 us; speedup 1.0000x reference)
//
#include <hip/hip_runtime.h>
#include <hip/hip_bf16.h>
#include <math.h>

// GNNAngle round 23: R22 (112.4us) + T5 s_setprio around every MFMA cluster.
// Mechanism: 3 independent blocks/CU sit at different phases (staging/ds_read,
// acos VALU, MFMA layers) - exactly the wave-role diversity setprio needs.
// Everything else byte-identical to R22 (3 barriers/chunk, ping-pong F buffer,
// deferred FINALSUM, zero-VGPR prefetch, vmem-free MLP, counted vmcnt).

#define NTHREADS 256    // 4 waves
#define CHUNK    16     // nodes per iteration per block
#define ASTRIDE  136    // f16 act row stride
#define PBLOCKS  768    // 3 per CU

typedef _Float16 f16;
typedef f16  f16x8 __attribute__((ext_vector_type(8)));
typedef f16  f16x4 __attribute__((ext_vector_type(4)));
typedef float f32x4 __attribute__((ext_vector_type(4)));

#define MFMA16(a, b, c) __builtin_amdgcn_mfma_f32_16x16x32_f16(a, b, c, 0, 0, 0)

__device__ __forceinline__ float fast_tanh(float x) {
    float e = __expf(2.0f * x);
    return 1.0f - 2.0f * __builtin_amdgcn_rcpf(e + 1.0f);
}

__device__ __forceinline__ float fast_acos(float x) {
    float ax = fabsf(x);
    float p = fmaf(-0.0187293f, ax, 0.0742610f);
    p = fmaf(p, ax, -0.2121144f);
    p = fmaf(p, ax, 1.5707288f);
    float r = sqrtf(1.0f - ax) * p;
    return (x >= 0.0f) ? r : (3.14159265358979f - r);
}

__device__ __forceinline__ void load_lds16(const float* g, float* l) {
    __builtin_amdgcn_global_load_lds(
        (__attribute__((address_space(1))) void*)(g),
        (__attribute__((address_space(3))) void*)(l), 16, 0, 0);
}

// ---- prep: W[i][j] (f32 [IN][128]) -> Wt[j][i] f16 [128][128], K zero-padded
__global__ void prep_weights(const float* __restrict__ W1,
                             const float* __restrict__ W2,
                             const float* __restrict__ W3,
                             f16* __restrict__ wt)
{
    int tid = blockIdx.x * 256 + threadIdx.x;
    if (tid >= 3 * 128 * 128) return;
    int layer = tid >> 14;
    int rem   = tid & 16383;
    int j     = rem >> 7;
    int i     = rem & 127;
    const float* W = (layer == 0) ? W1 : ((layer == 1) ? W2 : W3);
    int in_l = (layer == 0) ? 120 : 128;
    float v = (i < in_l) ? W[i * 128 + j] : 0.0f;
    wt[tid] = (f16)v;   // wt[layer][j][i]
}

__global__ __launch_bounds__(NTHREADS, 3)
void gnn_pipe(const float* __restrict__ edge_attr,
              const f16*   __restrict__ wt,
              const float* __restrict__ b1, const float* __restrict__ b2,
              const float* __restrict__ b3,
              const float* __restrict__ W4, const float* __restrict__ b4,
              float* __restrict__ out, int n_nodes, int nchunks)
{
    __shared__ __attribute__((aligned(16))) float stg[8192];        // 32 KB raw staging
    __shared__ __attribute__((aligned(16))) f16   actF0[16 * ASTRIDE];
    __shared__ __attribute__((aligned(16))) f16   actF1[16 * ASTRIDE];
    __shared__ __attribute__((aligned(16))) f16   actB[16 * ASTRIDE];
    __shared__ __attribute__((aligned(16))) float diag[4][4][16];
    __shared__ __attribute__((aligned(16))) float pbuf[16][4];
    __shared__ __attribute__((aligned(16))) float cbuf[512];        // b1|b2|b3|W4

    const int t  = threadIdx.x;
    const int w  = t >> 6;     // wave 0..3
    const int l  = t & 63;
    const int lr = l & 15;
    const int lg = l >> 4;

    // bias/W4 table (once)
    if (t < 128) {
        cbuf[t]       = b1[t];
        cbuf[128 + t] = b2[t];
        cbuf[256 + t] = b3[t];
        cbuf[384 + t] = W4[t];
    }
    // K-pad cols 120..127 of BOTH actF buffers
    {
        f16* fb = (t < 128) ? actF0 : actF1;
        const int tt = t & 127;
        fb[(tt >> 3) * ASTRIDE + 120 + (tt & 7)] = (f16)0.f;
    }
    const float bb4 = b4[0];

    // ---- preload ALL weight fragments (loop-invariant; wave owns j-tiles 2w,2w+1) ----
    #define LW(L, jj, kt) (*(const f16x8*)(wt + (L) * 16384 + ((w * 2 + (jj)) * 16 + lr) * 128 + (kt) * 32 + lg * 8))
    const f16x8 W000 = LW(0,0,0), W001 = LW(0,0,1), W002 = LW(0,0,2), W003 = LW(0,0,3);
    const f16x8 W010 = LW(0,1,0), W011 = LW(0,1,1), W012 = LW(0,1,2), W013 = LW(0,1,3);
    const f16x8 W100 = LW(1,0,0), W101 = LW(1,0,1), W102 = LW(1,0,2), W103 = LW(1,0,3);
    const f16x8 W110 = LW(1,1,0), W111 = LW(1,1,1), W112 = LW(1,1,2), W113 = LW(1,1,3);
    const f16x8 W200 = LW(2,0,0), W201 = LW(2,0,1), W202 = LW(2,0,2), W203 = LW(2,0,3);
    const f16x8 W210 = LW(2,1,0), W211 = LW(2,1,1), W212 = LW(2,1,2), W213 = LW(2,1,3);
    #undef LW

    // per-lane swizzled source offset within each staged 1KB window (bijective, coalesced)
    const int swsrc = (l * 16) ^ ((l >> 3) << 4);

    // wave w stages/computes nodes [ch*16 + w*4, +4) into its own stg region
    #define STAGE(ch_)                                                           \
        {                                                                        \
            const long n0_ = (long)(ch_) * CHUNK + w * 4;                        \
            _Pragma("unroll")                                                    \
            for (int i_ = 0; i_ < 8; ++i_) {                                     \
                long nd_ = n0_ + (i_ >> 1);                                      \
                if (nd_ >= n_nodes) nd_ = n_nodes - 1;                           \
                const float* gs_ = (const float*)((const char*)edge_attr         \
                                   + nd_ * 2048 + (i_ & 1) * 1024 + swsrc);      \
                load_lds16(gs_, &stg[w * 2048 + i_ * 256]);                      \
            }                                                                    \
        }

    #define LBAR()                                                               \
        {                                                                        \
            asm volatile("s_waitcnt lgkmcnt(0)" ::: "memory");                   \
            __builtin_amdgcn_s_barrier();                                        \
            __builtin_amdgcn_sched_barrier(0);                                   \
        }

    // MLP layer: biases from cbuf (LDS), weights from registers, acts LDS<->LDS
    // MFMA cluster wrapped in setprio(1)/(0) (T5: 3 blocks/CU at distinct phases)
    #define LAYER(SRC, DST, Wa0, Wa1, Wa2, Wa3, Wb0, Wb1, Wb2, Wb3, BOFF)       \
        {                                                                        \
            const f32x4 BV0 = *(const f32x4*)&cbuf[(BOFF) + (w * 2 + 0) * 16 + lg * 4]; \
            const f32x4 BV1 = *(const f32x4*)&cbuf[(BOFF) + (w * 2 + 1) * 16 + lg * 4]; \
            const f16* sr_ = (SRC) + lr * ASTRIDE + lg * 8;                      \
            f16x8 s0_ = *(const f16x8*)(sr_);                                    \
            f16x8 s1_ = *(const f16x8*)(sr_ + 32);                               \
            f16x8 s2_ = *(const f16x8*)(sr_ + 64);                               \
            f16x8 s3_ = *(const f16x8*)(sr_ + 96);                               \
            f32x4 a0_ = {0.f, 0.f, 0.f, 0.f}, a1_ = a0_;                         \
            __builtin_amdgcn_s_setprio(1);                                       \
            a0_ = MFMA16(Wa0, s0_, a0_); a1_ = MFMA16(Wb0, s0_, a1_);            \
            a0_ = MFMA16(Wa1, s1_, a0_); a1_ = MFMA16(Wb1, s1_, a1_);            \
            a0_ = MFMA16(Wa2, s2_, a0_); a1_ = MFMA16(Wb2, s2_, a1_);            \
            a0_ = MFMA16(Wa3, s3_, a0_); a1_ = MFMA16(Wb3, s3_, a1_);            \
            __builtin_amdgcn_s_setprio(0);                                       \
            f16x4 o0_, o1_;                                                      \
            _Pragma("unroll")                                                    \
            for (int r_ = 0; r_ < 4; ++r_) {                                     \
                o0_[r_] = (f16)fast_tanh(a0_[r_] + BV0[r_]);                     \
                o1_[r_] = (f16)fast_tanh(a1_[r_] + BV1[r_]);                     \
            }                                                                    \
            *(f16x4*)((DST) + lr * ASTRIDE + (w * 2 + 0) * 16 + lg * 4) = o0_;   \
            *(f16x4*)((DST) + lr * ASTRIDE + (w * 2 + 1) * 16 + lg * 4) = o1_;   \
        }

    // L3 fused: MFMA -> f32 tanh -> W4 partial dot -> lg-reduce -> pbuf[node][w]
    #define LAYER3(SRC)                                                          \
        {                                                                        \
            const f32x4 bvc0 = *(const f32x4*)&cbuf[256 + (w * 2 + 0) * 16 + lg * 4]; \
            const f32x4 bvc1 = *(const f32x4*)&cbuf[256 + (w * 2 + 1) * 16 + lg * 4]; \
            const f32x4 w4v0 = *(const f32x4*)&cbuf[384 + w * 32 + lg * 4];      \
            const f32x4 w4v1 = *(const f32x4*)&cbuf[384 + w * 32 + 16 + lg * 4]; \
            const f16* sr_ = (SRC) + lr * ASTRIDE + lg * 8;                      \
            f16x8 s0_ = *(const f16x8*)(sr_);                                    \
            f16x8 s1_ = *(const f16x8*)(sr_ + 32);                               \
            f16x8 s2_ = *(const f16x8*)(sr_ + 64);                               \
            f16x8 s3_ = *(const f16x8*)(sr_ + 96);                               \
            f32x4 a0_ = {0.f, 0.f, 0.f, 0.f}, a1_ = a0_;                         \
            __builtin_amdgcn_s_setprio(1);                                       \
            a0_ = MFMA16(W200, s0_, a0_); a1_ = MFMA16(W210, s0_, a1_);          \
            a0_ = MFMA16(W201, s1_, a0_); a1_ = MFMA16(W211, s1_, a1_);          \
            a0_ = MFMA16(W202, s2_, a0_); a1_ = MFMA16(W212, s2_, a1_);          \
            a0_ = MFMA16(W203, s3_, a0_); a1_ = MFMA16(W213, s3_, a1_);          \
            __builtin_amdgcn_s_setprio(0);                                       \
            float p_ = 0.f;                                                      \
            _Pragma("unroll")                                                    \
            for (int r_ = 0; r_ < 4; ++r_) {                                     \
                p_ = fmaf(fast_tanh(a0_[r_] + bvc0[r_]), w4v0[r_], p_);          \
                p_ = fmaf(fast_tanh(a1_[r_] + bvc1[r_]), w4v1[r_], p_);          \
            }                                                                    \
            p_ += __shfl_xor(p_, 16);                                            \
            p_ += __shfl_xor(p_, 32);                                            \
            if (l < 16) pbuf[lr][w] = p_;                                        \
        }

    // one store per WAVE (lanes 0..3 -> this wave's 4 nodes)
    #define FINALSUM(ch_)                                                        \
        {                                                                        \
            if (l < 4) {                                                         \
                const int nd_ = w * 4 + l;                                       \
                f32x4 pv_ = *(const f32x4*)&pbuf[nd_][0];                        \
                float s_ = (pv_[0] + pv_[1]) + (pv_[2] + pv_[3]);                \
                const long gn_ = (long)(ch_) * CHUNK + nd_;                      \
                if (gn_ < n_nodes)                                               \
                    out[gn_] = __builtin_amdgcn_rcpf(1.0f + __expf(-(s_ + bb4)));\
            }                                                                    \
        }

    long ch = blockIdx.x;
    STAGE(ch);
    asm volatile("s_waitcnt vmcnt(0)" ::: "memory");
    __builtin_amdgcn_sched_barrier(0);

    long prev = -1;
    int it = 0;
    for (; ch < nchunks; ch += PBLOCKS, ++it) {
        if (it) {
            // staging(ch) issued last iter; only this wave's FINALSUM store is
            // younger: vmcnt(1) + in-order retirement ==> staging complete.
            asm volatile("s_waitcnt vmcnt(1)" ::: "memory");
            __builtin_amdgcn_sched_barrier(0);
        }
        f16* F = (it & 1) ? actF1 : actF0;   // ping-pong FIN/L2/L3 buffer

        // ---- phase A: fragments from staged LDS (swizzled, conflict-free) ----
        const char* ws_ = (const char*)&stg[w * 2048];
        const int abase = lr * 128 + lg * 32;
        const int akey  = (lr & 7) << 4;
        f16x8 f0, f1, f2, f3;
        #define FRAG(fc, m_)                                                     \
            {                                                                    \
                float4 va = *(const float4*)(ws_ + (m_) * 2048 + (abase ^ akey));        \
                float4 vb = *(const float4*)(ws_ + (m_) * 2048 + ((abase + 16) ^ akey)); \
                fc[0]=(f16)va.x; fc[1]=(f16)va.y; fc[2]=(f16)va.z; fc[3]=(f16)va.w;      \
                fc[4]=(f16)vb.x; fc[5]=(f16)vb.y; fc[6]=(f16)vb.z; fc[7]=(f16)vb.w;      \
            }
        FRAG(f0, 0) FRAG(f1, 1) FRAG(f2, 2) FRAG(f3, 3)
        #undef FRAG

        // FRAG ds_reads hardware-complete before the DMA re-stage of this region
        asm volatile("s_waitcnt lgkmcnt(0)" ::: "memory");
        __builtin_amdgcn_sched_barrier(0);

        // ---- issue next chunk's staging into the SAME per-wave region ----
        const long nxt = ch + PBLOCKS;
        if (nxt < nchunks) STAGE(nxt);

        // ---- Gram MFMAs + diag + acos -> F ----
        f32x4 g0, g1, g2, g3;
        {
            f32x4 z = {0.f, 0.f, 0.f, 0.f};
            __builtin_amdgcn_s_setprio(1);
            g0 = MFMA16(f0, f0, z); g1 = MFMA16(f1, f1, z);
            g2 = MFMA16(f2, f2, z); g3 = MFMA16(f3, f3, z);
            __builtin_amdgcn_s_setprio(0);
        }
        if (lg == (lr >> 2)) {
            const int r = lr & 3;
            diag[w][0][lr] = __builtin_amdgcn_rsqf(g0[r] + 1e-24f);
            diag[w][1][lr] = __builtin_amdgcn_rsqf(g1[r] + 1e-24f);
            diag[w][2][lr] = __builtin_amdgcn_rsqf(g2[r] + 1e-24f);
            diag[w][3][lr] = __builtin_amdgcn_rsqf(g3[r] + 1e-24f);
        }
        asm volatile("s_waitcnt lgkmcnt(0)" ::: "memory");
        __builtin_amdgcn_sched_barrier(0);

        #define FIN(gc, c)                                                       \
            {                                                                    \
                const float rc = diag[w][c][lr];                                 \
                const f32x4 rr = *(const f32x4*)&diag[w][c][lg * 4];             \
                const int m_ = w * 4 + (c);                                      \
                const int col = lr;                                              \
                _Pragma("unroll")                                                \
                for (int r2 = 0; r2 < 4; ++r2) {                                 \
                    const int row = lg * 4 + r2;                                 \
                    float cv = gc[r2] * rr[r2] * rc;                             \
                    cv = fminf(fmaxf(cv, -1.0f + 1e-7f), 1.0f - 1e-7f);          \
                    float ang = fast_acos(cv);                                   \
                    if (row < col) {                                             \
                        const int p = 15*row - ((row*(row-1))>>1) + (col-row-1); \
                        F[m_ * ASTRIDE + p] = (f16)ang;                          \
                    }                                                            \
                }                                                                \
            }
        FIN(g0, 0) FIN(g1, 1) FIN(g2, 2) FIN(g3, 3)
        #undef FIN

        LBAR();   // #1: F visible block-wide; staging stays in flight

        // ---- deferred final store for the PREVIOUS chunk (pbuf now stable) ----
        if (it) FINALSUM(prev);

        // ---- phase B: L1, L2 (vmem-free), L3 fused with final dot ----
        LAYER(F, actB, W000, W001, W002, W003, W010, W011, W012, W013, 0);
        LBAR();   // #2
        LAYER(actB, F, W100, W101, W102, W103, W110, W111, W112, W113, 128);
        LBAR();   // #3
        LAYER3(F);
        // no trailing barrier: pbuf consumed only after next iter's LBAR #1;
        // F rewritten only two iterations later (ping-pong + 3 barriers).

        prev = ch;
    }
    // epilogue: last chunk's final (needs one barrier for pbuf visibility)
    LBAR();
    if (prev >= 0) FINALSUM(prev);

    #undef STAGE
    #undef LBAR
    #undef LAYER
    #undef LAYER3
    #undef FINALSUM
}

extern "C" void kernel_launch(void* const* d_in, const int* in_sizes, int n_in,
                              void* d_out, int out_size, void* d_ws, size_t ws_size,
                              hipStream_t stream) {
    // inputs: 0:x 1:edge_index 2:edge_attr 3:k 4:W1 5:b1 6:W2 7:b2 8:W3 9:b3 10:W4 11:b4
    const float* edge_attr = (const float*)d_in[2];
    const float* W1 = (const float*)d_in[4];
    const float* b1 = (const float*)d_in[5];
    const float* W2 = (const float*)d_in[6];
    const float* b2 = (const float*)d_in[7];
    const float* W3 = (const float*)d_in[8];
    const float* b3 = (const float*)d_in[9];
    const float* W4 = (const float*)d_in[10];
    const float* b4 = (const float*)d_in[11];
    float* out = (float*)d_out;
    f16* wt = (f16*)d_ws;                        // 3*128*128 f16 = 96 KB

    const int n_nodes = in_sizes[2] / 512;       // E*D / (16*32)
    const int nchunks = (n_nodes + CHUNK - 1) / CHUNK;
    const int blocks  = PBLOCKS < nchunks ? PBLOCKS : nchunks;

    prep_weights<<<(3 * 128 * 128 + 255) / 256, 256, 0, stream>>>(W1, W2, W3, wt);

    gnn_pipe<<<blocks, NTHREADS, 0, stream>>>(
        edge_attr, wt, b1, b2, b3, W4, b4, out, n_nodes, nchunks);
}

// Round 24
// 111.885 us; speedup vs baseline: 1.0251x; 1.0251x over previous
//
#include <hip/hip_runtime.h>
#include <hip/hip_bf16.h>
#include <math.h>

// GNNAngle round 24: REVERT to R22 verbatim (112.4us champion). R23's setprio
// was null-to-negative (114.7) - lockstep barrier schedule has no wave-role
// diversity for the scheduler to arbitrate (matches guide m190).
// R22 = persistent pipeline: zero-VGPR cross-chunk prefetch (global_load_lds,
// single 32KB staging buffer re-staged after FRAG reads), weights in 96 VGPR
// (vmem-free MLP => counted vmcnt discipline works), raw s_barrier + lgkm
// fences (no vmcnt drain), 3 barriers/chunk (ping-pong F buffer + deferred
// FINALSUM), fused L3+W4 dot. 3 blocks/CU (48KB LDS).

#define NTHREADS 256    // 4 waves
#define CHUNK    16     // nodes per iteration per block
#define ASTRIDE  136    // f16 act row stride
#define PBLOCKS  768    // 3 per CU

typedef _Float16 f16;
typedef f16  f16x8 __attribute__((ext_vector_type(8)));
typedef f16  f16x4 __attribute__((ext_vector_type(4)));
typedef float f32x4 __attribute__((ext_vector_type(4)));

#define MFMA16(a, b, c) __builtin_amdgcn_mfma_f32_16x16x32_f16(a, b, c, 0, 0, 0)

__device__ __forceinline__ float fast_tanh(float x) {
    float e = __expf(2.0f * x);
    return 1.0f - 2.0f * __builtin_amdgcn_rcpf(e + 1.0f);
}

__device__ __forceinline__ float fast_acos(float x) {
    float ax = fabsf(x);
    float p = fmaf(-0.0187293f, ax, 0.0742610f);
    p = fmaf(p, ax, -0.2121144f);
    p = fmaf(p, ax, 1.5707288f);
    float r = sqrtf(1.0f - ax) * p;
    return (x >= 0.0f) ? r : (3.14159265358979f - r);
}

__device__ __forceinline__ void load_lds16(const float* g, float* l) {
    __builtin_amdgcn_global_load_lds(
        (__attribute__((address_space(1))) void*)(g),
        (__attribute__((address_space(3))) void*)(l), 16, 0, 0);
}

// ---- prep: W[i][j] (f32 [IN][128]) -> Wt[j][i] f16 [128][128], K zero-padded
__global__ void prep_weights(const float* __restrict__ W1,
                             const float* __restrict__ W2,
                             const float* __restrict__ W3,
                             f16* __restrict__ wt)
{
    int tid = blockIdx.x * 256 + threadIdx.x;
    if (tid >= 3 * 128 * 128) return;
    int layer = tid >> 14;
    int rem   = tid & 16383;
    int j     = rem >> 7;
    int i     = rem & 127;
    const float* W = (layer == 0) ? W1 : ((layer == 1) ? W2 : W3);
    int in_l = (layer == 0) ? 120 : 128;
    float v = (i < in_l) ? W[i * 128 + j] : 0.0f;
    wt[tid] = (f16)v;   // wt[layer][j][i]
}

__global__ __launch_bounds__(NTHREADS, 3)
void gnn_pipe(const float* __restrict__ edge_attr,
              const f16*   __restrict__ wt,
              const float* __restrict__ b1, const float* __restrict__ b2,
              const float* __restrict__ b3,
              const float* __restrict__ W4, const float* __restrict__ b4,
              float* __restrict__ out, int n_nodes, int nchunks)
{
    __shared__ __attribute__((aligned(16))) float stg[8192];        // 32 KB raw staging
    __shared__ __attribute__((aligned(16))) f16   actF0[16 * ASTRIDE];
    __shared__ __attribute__((aligned(16))) f16   actF1[16 * ASTRIDE];
    __shared__ __attribute__((aligned(16))) f16   actB[16 * ASTRIDE];
    __shared__ __attribute__((aligned(16))) float diag[4][4][16];
    __shared__ __attribute__((aligned(16))) float pbuf[16][4];
    __shared__ __attribute__((aligned(16))) float cbuf[512];        // b1|b2|b3|W4

    const int t  = threadIdx.x;
    const int w  = t >> 6;     // wave 0..3
    const int l  = t & 63;
    const int lr = l & 15;
    const int lg = l >> 4;

    // bias/W4 table (once)
    if (t < 128) {
        cbuf[t]       = b1[t];
        cbuf[128 + t] = b2[t];
        cbuf[256 + t] = b3[t];
        cbuf[384 + t] = W4[t];
    }
    // K-pad cols 120..127 of BOTH actF buffers (FIN never writes them; W1 pad
    // rows are zero so later stale L2 outputs there are harmless)
    {
        f16* fb = (t < 128) ? actF0 : actF1;
        const int tt = t & 127;
        fb[(tt >> 3) * ASTRIDE + 120 + (tt & 7)] = (f16)0.f;
    }
    const float bb4 = b4[0];

    // ---- preload ALL weight fragments (loop-invariant; wave owns j-tiles 2w,2w+1) ----
    #define LW(L, jj, kt) (*(const f16x8*)(wt + (L) * 16384 + ((w * 2 + (jj)) * 16 + lr) * 128 + (kt) * 32 + lg * 8))
    const f16x8 W000 = LW(0,0,0), W001 = LW(0,0,1), W002 = LW(0,0,2), W003 = LW(0,0,3);
    const f16x8 W010 = LW(0,1,0), W011 = LW(0,1,1), W012 = LW(0,1,2), W013 = LW(0,1,3);
    const f16x8 W100 = LW(1,0,0), W101 = LW(1,0,1), W102 = LW(1,0,2), W103 = LW(1,0,3);
    const f16x8 W110 = LW(1,1,0), W111 = LW(1,1,1), W112 = LW(1,1,2), W113 = LW(1,1,3);
    const f16x8 W200 = LW(2,0,0), W201 = LW(2,0,1), W202 = LW(2,0,2), W203 = LW(2,0,3);
    const f16x8 W210 = LW(2,1,0), W211 = LW(2,1,1), W212 = LW(2,1,2), W213 = LW(2,1,3);
    #undef LW

    // per-lane swizzled source offset within each staged 1KB window (bijective, coalesced)
    const int swsrc = (l * 16) ^ ((l >> 3) << 4);

    // wave w stages/computes nodes [ch*16 + w*4, +4) into its own stg region
    #define STAGE(ch_)                                                           \
        {                                                                        \
            const long n0_ = (long)(ch_) * CHUNK + w * 4;                        \
            _Pragma("unroll")                                                    \
            for (int i_ = 0; i_ < 8; ++i_) {                                     \
                long nd_ = n0_ + (i_ >> 1);                                      \
                if (nd_ >= n_nodes) nd_ = n_nodes - 1;                           \
                const float* gs_ = (const float*)((const char*)edge_attr         \
                                   + nd_ * 2048 + (i_ & 1) * 1024 + swsrc);      \
                load_lds16(gs_, &stg[w * 2048 + i_ * 256]);                      \
            }                                                                    \
        }

    #define LBAR()                                                               \
        {                                                                        \
            asm volatile("s_waitcnt lgkmcnt(0)" ::: "memory");                   \
            __builtin_amdgcn_s_barrier();                                        \
            __builtin_amdgcn_sched_barrier(0);                                   \
        }

    // MLP layer: biases from cbuf (LDS), weights from registers, acts LDS<->LDS
    #define LAYER(SRC, DST, Wa0, Wa1, Wa2, Wa3, Wb0, Wb1, Wb2, Wb3, BOFF)       \
        {                                                                        \
            const f32x4 BV0 = *(const f32x4*)&cbuf[(BOFF) + (w * 2 + 0) * 16 + lg * 4]; \
            const f32x4 BV1 = *(const f32x4*)&cbuf[(BOFF) + (w * 2 + 1) * 16 + lg * 4]; \
            const f16* sr_ = (SRC) + lr * ASTRIDE + lg * 8;                      \
            f16x8 s0_ = *(const f16x8*)(sr_);                                    \
            f16x8 s1_ = *(const f16x8*)(sr_ + 32);                               \
            f16x8 s2_ = *(const f16x8*)(sr_ + 64);                               \
            f16x8 s3_ = *(const f16x8*)(sr_ + 96);                               \
            f32x4 a0_ = {0.f, 0.f, 0.f, 0.f}, a1_ = a0_;                         \
            a0_ = MFMA16(Wa0, s0_, a0_); a1_ = MFMA16(Wb0, s0_, a1_);            \
            a0_ = MFMA16(Wa1, s1_, a0_); a1_ = MFMA16(Wb1, s1_, a1_);            \
            a0_ = MFMA16(Wa2, s2_, a0_); a1_ = MFMA16(Wb2, s2_, a1_);            \
            a0_ = MFMA16(Wa3, s3_, a0_); a1_ = MFMA16(Wb3, s3_, a1_);            \
            f16x4 o0_, o1_;                                                      \
            _Pragma("unroll")                                                    \
            for (int r_ = 0; r_ < 4; ++r_) {                                     \
                o0_[r_] = (f16)fast_tanh(a0_[r_] + BV0[r_]);                     \
                o1_[r_] = (f16)fast_tanh(a1_[r_] + BV1[r_]);                     \
            }                                                                    \
            *(f16x4*)((DST) + lr * ASTRIDE + (w * 2 + 0) * 16 + lg * 4) = o0_;   \
            *(f16x4*)((DST) + lr * ASTRIDE + (w * 2 + 1) * 16 + lg * 4) = o1_;   \
        }

    // L3 fused: MFMA -> f32 tanh -> W4 partial dot -> lg-reduce -> pbuf[node][w]
    #define LAYER3(SRC)                                                          \
        {                                                                        \
            const f32x4 bvc0 = *(const f32x4*)&cbuf[256 + (w * 2 + 0) * 16 + lg * 4]; \
            const f32x4 bvc1 = *(const f32x4*)&cbuf[256 + (w * 2 + 1) * 16 + lg * 4]; \
            const f32x4 w4v0 = *(const f32x4*)&cbuf[384 + w * 32 + lg * 4];      \
            const f32x4 w4v1 = *(const f32x4*)&cbuf[384 + w * 32 + 16 + lg * 4]; \
            const f16* sr_ = (SRC) + lr * ASTRIDE + lg * 8;                      \
            f16x8 s0_ = *(const f16x8*)(sr_);                                    \
            f16x8 s1_ = *(const f16x8*)(sr_ + 32);                               \
            f16x8 s2_ = *(const f16x8*)(sr_ + 64);                               \
            f16x8 s3_ = *(const f16x8*)(sr_ + 96);                               \
            f32x4 a0_ = {0.f, 0.f, 0.f, 0.f}, a1_ = a0_;                         \
            a0_ = MFMA16(W200, s0_, a0_); a1_ = MFMA16(W210, s0_, a1_);          \
            a0_ = MFMA16(W201, s1_, a0_); a1_ = MFMA16(W211, s1_, a1_);          \
            a0_ = MFMA16(W202, s2_, a0_); a1_ = MFMA16(W212, s2_, a1_);          \
            a0_ = MFMA16(W203, s3_, a0_); a1_ = MFMA16(W213, s3_, a1_);          \
            float p_ = 0.f;                                                      \
            _Pragma("unroll")                                                    \
            for (int r_ = 0; r_ < 4; ++r_) {                                     \
                p_ = fmaf(fast_tanh(a0_[r_] + bvc0[r_]), w4v0[r_], p_);          \
                p_ = fmaf(fast_tanh(a1_[r_] + bvc1[r_]), w4v1[r_], p_);          \
            }                                                                    \
            p_ += __shfl_xor(p_, 16);                                            \
            p_ += __shfl_xor(p_, 32);                                            \
            if (l < 16) pbuf[lr][w] = p_;                                        \
        }

    // one store per WAVE (lanes 0..3 -> this wave's 4 nodes)
    #define FINALSUM(ch_)                                                        \
        {                                                                        \
            if (l < 4) {                                                         \
                const int nd_ = w * 4 + l;                                       \
                f32x4 pv_ = *(const f32x4*)&pbuf[nd_][0];                        \
                float s_ = (pv_[0] + pv_[1]) + (pv_[2] + pv_[3]);                \
                const long gn_ = (long)(ch_) * CHUNK + nd_;                      \
                if (gn_ < n_nodes)                                               \
                    out[gn_] = __builtin_amdgcn_rcpf(1.0f + __expf(-(s_ + bb4)));\
            }                                                                    \
        }

    long ch = blockIdx.x;
    STAGE(ch);
    asm volatile("s_waitcnt vmcnt(0)" ::: "memory");
    __builtin_amdgcn_sched_barrier(0);

    long prev = -1;
    int it = 0;
    for (; ch < nchunks; ch += PBLOCKS, ++it) {
        if (it) {
            // staging(ch) issued last iter; only this wave's FINALSUM store is
            // younger: vmcnt(1) + in-order retirement ==> staging complete.
            asm volatile("s_waitcnt vmcnt(1)" ::: "memory");
            __builtin_amdgcn_sched_barrier(0);
        }
        f16* F = (it & 1) ? actF1 : actF0;   // ping-pong FIN/L2/L3 buffer

        // ---- phase A: fragments from staged LDS (swizzled, conflict-free) ----
        const char* ws_ = (const char*)&stg[w * 2048];
        const int abase = lr * 128 + lg * 32;
        const int akey  = (lr & 7) << 4;
        f16x8 f0, f1, f2, f3;
        #define FRAG(fc, m_)                                                     \
            {                                                                    \
                float4 va = *(const float4*)(ws_ + (m_) * 2048 + (abase ^ akey));        \
                float4 vb = *(const float4*)(ws_ + (m_) * 2048 + ((abase + 16) ^ akey)); \
                fc[0]=(f16)va.x; fc[1]=(f16)va.y; fc[2]=(f16)va.z; fc[3]=(f16)va.w;      \
                fc[4]=(f16)vb.x; fc[5]=(f16)vb.y; fc[6]=(f16)vb.z; fc[7]=(f16)vb.w;      \
            }
        FRAG(f0, 0) FRAG(f1, 1) FRAG(f2, 2) FRAG(f3, 3)
        #undef FRAG

        // FRAG ds_reads hardware-complete before the DMA re-stage of this region
        asm volatile("s_waitcnt lgkmcnt(0)" ::: "memory");
        __builtin_amdgcn_sched_barrier(0);

        // ---- issue next chunk's staging into the SAME per-wave region ----
        const long nxt = ch + PBLOCKS;
        if (nxt < nchunks) STAGE(nxt);

        // ---- Gram MFMAs + diag + acos -> F ----
        f32x4 g0, g1, g2, g3;
        {
            f32x4 z = {0.f, 0.f, 0.f, 0.f};
            g0 = MFMA16(f0, f0, z); g1 = MFMA16(f1, f1, z);
            g2 = MFMA16(f2, f2, z); g3 = MFMA16(f3, f3, z);
        }
        if (lg == (lr >> 2)) {
            const int r = lr & 3;
            diag[w][0][lr] = __builtin_amdgcn_rsqf(g0[r] + 1e-24f);
            diag[w][1][lr] = __builtin_amdgcn_rsqf(g1[r] + 1e-24f);
            diag[w][2][lr] = __builtin_amdgcn_rsqf(g2[r] + 1e-24f);
            diag[w][3][lr] = __builtin_amdgcn_rsqf(g3[r] + 1e-24f);
        }
        asm volatile("s_waitcnt lgkmcnt(0)" ::: "memory");
        __builtin_amdgcn_sched_barrier(0);

        #define FIN(gc, c)                                                       \
            {                                                                    \
                const float rc = diag[w][c][lr];                                 \
                const f32x4 rr = *(const f32x4*)&diag[w][c][lg * 4];             \
                const int m_ = w * 4 + (c);                                      \
                const int col = lr;                                              \
                _Pragma("unroll")                                                \
                for (int r2 = 0; r2 < 4; ++r2) {                                 \
                    const int row = lg * 4 + r2;                                 \
                    float cv = gc[r2] * rr[r2] * rc;                             \
                    cv = fminf(fmaxf(cv, -1.0f + 1e-7f), 1.0f - 1e-7f);          \
                    float ang = fast_acos(cv);                                   \
                    if (row < col) {                                             \
                        const int p = 15*row - ((row*(row-1))>>1) + (col-row-1); \
                        F[m_ * ASTRIDE + p] = (f16)ang;                          \
                    }                                                            \
                }                                                                \
            }
        FIN(g0, 0) FIN(g1, 1) FIN(g2, 2) FIN(g3, 3)
        #undef FIN

        LBAR();   // #1: F visible block-wide; staging stays in flight

        // ---- deferred final store for the PREVIOUS chunk (pbuf now stable) ----
        if (it) FINALSUM(prev);

        // ---- phase B: L1, L2 (vmem-free), L3 fused with final dot ----
        LAYER(F, actB, W000, W001, W002, W003, W010, W011, W012, W013, 0);
        LBAR();   // #2
        LAYER(actB, F, W100, W101, W102, W103, W110, W111, W112, W113, 128);
        LBAR();   // #3
        LAYER3(F);
        // no trailing barrier: pbuf consumed only after next iter's LBAR #1;
        // F rewritten only two iterations later (ping-pong + 3 barriers).

        prev = ch;
    }
    // epilogue: last chunk's final (needs one barrier for pbuf visibility)
    LBAR();
    if (prev >= 0) FINALSUM(prev);

    #undef STAGE
    #undef LBAR
    #undef LAYER
    #undef LAYER3
    #undef FINALSUM
}

extern "C" void kernel_launch(void* const* d_in, const int* in_sizes, int n_in,
                              void* d_out, int out_size, void* d_ws, size_t ws_size,
                              hipStream_t stream) {
    // inputs: 0:x 1:edge_index 2:edge_attr 3:k 4:W1 5:b1 6:W2 7:b2 8:W3 9:b3 10:W4 11:b4
    const float* edge_attr = (const float*)d_in[2];
    const float* W1 = (const float*)d_in[4];
    const float* b1 = (const float*)d_in[5];
    const float* W2 = (const float*)d_in[6];
    const float* b2 = (const float*)d_in[7];
    const float* W3 = (const float*)d_in[8];
    const float* b3 = (const float*)d_in[9];
    const float* W4 = (const float*)d_in[10];
    const float* b4 = (const float*)d_in[11];
    float* out = (float*)d_out;
    f16* wt = (f16*)d_ws;                        // 3*128*128 f16 = 96 KB

    const int n_nodes = in_sizes[2] / 512;       // E*D / (16*32)
    const int nchunks = (n_nodes + CHUNK - 1) / CHUNK;
    const int blocks  = PBLOCKS < nchunks ? PBLOCKS : nchunks;

    prep_weights<<<(3 * 128 * 128 + 255) / 256, 256, 0, stream>>>(W1, W2, W3, wt);

    gnn_pipe<<<blocks, NTHREADS, 0, stream>>>(
        edge_attr, wt, b1, b2, b3, W4, b4, out, n_nodes, nchunks);
}